// Round 12
// baseline (4373.304 us; speedup 1.0000x reference)
//
#include <hip/hip_runtime.h>

#define NN 384
#define ARR_CAP 6000
#define MARKV 0x7FFFFFFF          // minv sentinel: column used in current tree
#define BIG0  0x7FFFFFF0          // minv init (must differ from MARKV)
#define SATK  ((1 << 28) - 1)     // 28-bit key: covers full cost range (<2^27.5) -> real
                                  // values NEVER saturate; only MARKV/BIG0 map to SATK.
// Costs are stored pre-scaled by 2^24 and converted to i32 in place: f32 value
// c*2^24 is an exact integer < 2^28. All solver arithmetic is exact i32 math ->
// identical optimum to f64-on-f32 (reference) solve (unique optimum w.p. 1).
//
// LAP solver split into 3 kernels (init1 = CR+RT, init2 = ARR, sap = Dijkstra)
// for rocprof phase attribution. THIS ROUND: ARR_CAP 1000 -> 6000, everything
// else byte-identical to round 11 (no-spec SAP).

// uniform-index register-array write helpers
#define SETV6(a, k, val) do{ switch(k){ \
  case 0: a[0]=(val); break; case 1: a[1]=(val); break; case 2: a[2]=(val); break; \
  case 3: a[3]=(val); break; case 4: a[4]=(val); break; default: a[5]=(val); } }while(0)

__device__ __forceinline__ void lds_fence() {
  // single-wave block: lgkmcnt(0) orders LDS cross-lane; no barrier, no vmcnt drain
  asm volatile("s_waitcnt lgkmcnt(0)" ::: "memory");
}

// branchless 6-way select of a[k] for uniform k (5 cndmask, no branches)
__device__ __forceinline__ int sel6b(const int (&a)[6], int k) {
  int x01 = (k & 1) ? a[1] : a[0];
  int x23 = (k & 1) ? a[3] : a[2];
  int x45 = (k & 1) ? a[5] : a[4];
  int xlo = (k & 2) ? x23 : x01;
  return (k & 4) ? x45 : xlo;
}

template<int CTRL>
__device__ __forceinline__ int dpp_i32(int x) {
  // lanes without a valid DPP source keep INT_MAX -> never win the min
  return __builtin_amdgcn_update_dpp(0x7FFFFFFF, x, CTRL, 0xF, 0xF, false);
}

// stages: xor1, xor2 (quads), ror4, ror8 (row of 16), bcast15, bcast31 (merge rows)
__device__ __forceinline__ int wave_min_i32(int m) {
#define ST(C) { int o = dpp_i32<C>(m); m = min(m, o); }
  ST(0xB1) ST(0x4E) ST(0x124) ST(0x128) ST(0x142) ST(0x143)
#undef ST
  return __builtin_amdgcn_readlane(m, 63);
}

// (min, second-min) over disjoint per-lane candidate sets; results broadcast
__device__ __forceinline__ void wave_min2_i32(int& m1, int& m2) {
#define ST(C) { int o1 = dpp_i32<C>(m1); int o2 = dpp_i32<C>(m2); \
                int hi = max(m1, o1); m1 = min(m1, o1); m2 = min(min(m2, o2), hi); }
  ST(0xB1) ST(0x4E) ST(0x124) ST(0x128) ST(0x142) ST(0x143)
#undef ST
  m1 = __builtin_amdgcn_readlane(m1, 63);
  m2 = __builtin_amdgcn_readlane(m2, 63);
}

// ---------------- row norms: 4 layers fused, X is [768][K] each -----------------
__global__ __launch_bounds__(256) void row_norms_k(const float* __restrict__ x0,
                                                   const float* __restrict__ x1,
                                                   const float* __restrict__ x2,
                                                   const float* __restrict__ x3,
                                                   float* __restrict__ out,
                                                   int K0, int K1, int K2, int K3) {
  int layer = blockIdx.y;
  const float* X = layer == 0 ? x0 : layer == 1 ? x1 : layer == 2 ? x2 : x3;
  int K = layer == 0 ? K0 : layer == 1 ? K1 : layer == 2 ? K2 : K3;
  int row = blockIdx.x;
  int tid = threadIdx.x;
  const float4* xp = (const float4*)(X + (size_t)row * K);
  int K4 = K >> 2;
  float s = 0.f;
  for (int k = tid; k < K4; k += 256) {
    float4 x = xp[k];
    s = fmaf(x.x, x.x, s); s = fmaf(x.y, x.y, s);
    s = fmaf(x.z, x.z, s); s = fmaf(x.w, x.w, s);
  }
  __shared__ float red[256];
  red[tid] = s;
  __syncthreads();
  for (int st = 128; st > 0; st >>= 1) {
    if (tid < st) red[tid] += red[tid + st];
    __syncthreads();
  }
  if (tid == 0) out[layer * 768 + row] = red[0];
}

// ---------------- split-K GEMM partial: 64x64 tile, K-slice ---------------------
__global__ __launch_bounds__(256) void gemm_partial_k(const float* __restrict__ A,
                                                      const float* __restrict__ B,
                                                      float* __restrict__ pbuf,
                                                      int K, int kslice, int S) {
  __shared__ float As[16][64];
  __shared__ float Bs[16][64];
  const int tid = threadIdx.x;
  const int row0 = blockIdx.y * 64;
  const int col0 = blockIdx.x * 64;
  const int sz = blockIdx.z;
  const int tm = (tid >> 4) << 2;
  const int tn = (tid & 15) << 2;
  const int lr = tid >> 2;
  const int lk = (tid & 3) << 2;
  const float* ap = A + (size_t)(row0 + lr) * K + (size_t)sz * kslice + lk;
  const float* bp = B + (size_t)(col0 + lr) * K + (size_t)sz * kslice + lk;
  float acc[4][4] = {};
  for (int k0 = 0; k0 < kslice; k0 += 16) {
    float4 av = *(const float4*)(ap + k0);
    float4 bv = *(const float4*)(bp + k0);
    __syncthreads();
    As[lk + 0][lr] = av.x; As[lk + 1][lr] = av.y; As[lk + 2][lr] = av.z; As[lk + 3][lr] = av.w;
    Bs[lk + 0][lr] = bv.x; Bs[lk + 1][lr] = bv.y; Bs[lk + 2][lr] = bv.z; Bs[lk + 3][lr] = bv.w;
    __syncthreads();
    float t[4][4] = {};
#pragma unroll
    for (int kk = 0; kk < 16; ++kk) {
      float4 a = *(const float4*)&As[kk][tm];
      float4 b = *(const float4*)&Bs[kk][tn];
      t[0][0] = fmaf(a.x, b.x, t[0][0]); t[0][1] = fmaf(a.x, b.y, t[0][1]);
      t[0][2] = fmaf(a.x, b.z, t[0][2]); t[0][3] = fmaf(a.x, b.w, t[0][3]);
      t[1][0] = fmaf(a.y, b.x, t[1][0]); t[1][1] = fmaf(a.y, b.y, t[1][1]);
      t[1][2] = fmaf(a.y, b.z, t[1][2]); t[1][3] = fmaf(a.y, b.w, t[1][3]);
      t[2][0] = fmaf(a.z, b.x, t[2][0]); t[2][1] = fmaf(a.z, b.y, t[2][1]);
      t[2][2] = fmaf(a.z, b.z, t[2][2]); t[2][3] = fmaf(a.z, b.w, t[2][3]);
      t[3][0] = fmaf(a.w, b.x, t[3][0]); t[3][1] = fmaf(a.w, b.y, t[3][1]);
      t[3][2] = fmaf(a.w, b.z, t[3][2]); t[3][3] = fmaf(a.w, b.w, t[3][3]);
    }
#pragma unroll
    for (int m = 0; m < 4; ++m)
#pragma unroll
      for (int n = 0; n < 4; ++n) acc[m][n] += t[m][n];
  }
  float* pb = pbuf + (((size_t)(blockIdx.y * 6 + blockIdx.x) * S + sz) << 12);
#pragma unroll
  for (int m = 0; m < 4; ++m)
#pragma unroll
    for (int n = 0; n < 4; ++n)
      pb[((tm + m) << 6) | (tn + n)] = acc[m][n];
}

// ---------------- finalize cost from partials; output scaled by 2^24 ------------
__global__ __launch_bounds__(256) void cost_finalize_k(const float* __restrict__ pbuf,
                                                       const float* __restrict__ sa,
                                                       const float* __restrict__ sb,
                                                       float* __restrict__ C,
                                                       int S, float inv_ds) {
  int idx = blockIdx.x * 256 + threadIdx.x;
  if (idx >= NN * NN) return;
  int i = idx / NN;
  int j = idx - i * NN;
  int t = (i >> 6) * 6 + (j >> 6);
  int w = ((i & 63) << 6) | (j & 63);
  const float* p = pbuf + ((size_t)t * S << 12) + w;
  float dot = 0.f;
  for (int s = 0; s < S; ++s) dot += p[(size_t)s << 12];
  float sq = (sa[i] - 2.0f * dot) + sb[j];
  C[idx] = fmaxf(sq, 0.0f) * inv_ds;   // inv_ds = 2^24/K (pow2) -> exact scaling
}

// ---------------- fallback single-pass cost GEMM (if ws too small) --------------
__global__ __launch_bounds__(256) void gemm_cost_k(const float* __restrict__ A,
                                                   const float* __restrict__ B,
                                                   const float* __restrict__ sa,
                                                   const float* __restrict__ sb,
                                                   float* __restrict__ C,
                                                   int K, float inv_ds) {
  __shared__ float As[16][64];
  __shared__ float Bs[16][64];
  const int tid = threadIdx.x;
  const int row0 = blockIdx.y * 64;
  const int col0 = blockIdx.x * 64;
  const int tm = (tid >> 4) << 2;
  const int tn = (tid & 15) << 2;
  const int lr = tid >> 2;
  const int lk = (tid & 3) << 2;
  const float* ap = A + (size_t)(row0 + lr) * K + lk;
  const float* bp = B + (size_t)(col0 + lr) * K + lk;
  float acc[4][4] = {};
  for (int k0 = 0; k0 < K; k0 += 16) {
    float4 av = *(const float4*)(ap + k0);
    float4 bv = *(const float4*)(bp + k0);
    __syncthreads();
    As[lk + 0][lr] = av.x; As[lk + 1][lr] = av.y; As[lk + 2][lr] = av.z; As[lk + 3][lr] = av.w;
    Bs[lk + 0][lr] = bv.x; Bs[lk + 1][lr] = bv.y; Bs[lk + 2][lr] = bv.z; Bs[lk + 3][lr] = bv.w;
    __syncthreads();
#pragma unroll
    for (int kk = 0; kk < 16; ++kk) {
      float4 a = *(const float4*)&As[kk][tm];
      float4 b = *(const float4*)&Bs[kk][tn];
      acc[0][0] = fmaf(a.x, b.x, acc[0][0]); acc[0][1] = fmaf(a.x, b.y, acc[0][1]);
      acc[0][2] = fmaf(a.x, b.z, acc[0][2]); acc[0][3] = fmaf(a.x, b.w, acc[0][3]);
      acc[1][0] = fmaf(a.y, b.x, acc[1][0]); acc[1][1] = fmaf(a.y, b.y, acc[1][1]);
      acc[1][2] = fmaf(a.y, b.z, acc[1][2]); acc[1][3] = fmaf(a.y, b.w, acc[1][3]);
      acc[2][0] = fmaf(a.z, b.x, acc[2][0]); acc[2][1] = fmaf(a.z, b.y, acc[2][1]);
      acc[2][2] = fmaf(a.z, b.z, acc[2][2]); acc[2][3] = fmaf(a.z, b.w, acc[2][3]);
      acc[3][0] = fmaf(a.w, b.x, acc[3][0]); acc[3][1] = fmaf(a.w, b.y, acc[3][1]);
      acc[3][2] = fmaf(a.w, b.z, acc[3][2]); acc[3][3] = fmaf(a.w, b.w, acc[3][3]);
    }
  }
#pragma unroll
  for (int m = 0; m < 4; ++m) {
    int i = row0 + tm + m;
    float sai = sa[i];
#pragma unroll
    for (int n = 0; n < 4; ++n) {
      int j = col0 + tn + n;
      float sq = (sai - 2.0f * acc[m][n]) + sb[j];
      C[i * NN + j] = fmaxf(sq, 0.0f) * inv_ds;
    }
  }
}

// ---- combine (f32, rounding identical to reference since scale is pow2) then
//      convert ALL 5 matrices to i32 IN PLACE (exact: values are integral f32) --
__global__ __launch_bounds__(256) void combine_k(float* __restrict__ cost) {
  int idx = blockIdx.x * 256 + threadIdx.x;
  if (idx < NN * NN) {
    float c0 = cost[idx];
    float c1 = cost[1 * NN * NN + idx];
    float c2 = cost[2 * NN * NN + idx];
    float c3 = cost[3 * NN * NN + idx];
    float cc = c0 + 0.5f * c1 + 0.25f * c2 + 0.125f * c3;
    int* ci = (int*)cost;
    ci[idx] = (int)c0;
    ci[1 * NN * NN + idx] = (int)c1;
    ci[2 * NN * NN + idx] = (int)c2;
    ci[3 * NN * NN + idx] = (int)c3;
    ci[4 * NN * NN + idx] = (int)cc;
  }
}

// st layout per problem (stride 4*NN ints): [0,NN)=v  [NN,2NN)=u  [2NN,3NN)=mrow
// [3NN,4NN)=rowfree
// ---------------- LAP kernel 1: column reduction + reduction transfer -----------
__global__ __launch_bounds__(64) void lap_init1_k(const int* __restrict__ costs,
                                                  int* __restrict__ st) {
  const int prob = blockIdx.x;
  const int* __restrict__ Ci = costs + (size_t)prob * NN * NN;
  int* __restrict__ stp = st + (size_t)prob * 4 * NN;
  const int lane = threadIdx.x;

  __shared__ int u_si[NN];
  __shared__ int mrow_s[NN];
  __shared__ int rowpick_s[NN];
  __shared__ int rowfree_s[NN];
  __shared__ int list_s[NN];

  int vv[6];

  // ---- Phase 1: column reduction ---------------------------------------------
  int vmin[6]; int imin[6];
#pragma unroll
  for (int k = 0; k < 6; ++k) { vmin[k] = 0x7FFFFFFF; imin[k] = 0; }
  {
    const int* p = Ci + lane;
#pragma unroll 8
    for (int i = 0; i < NN; ++i) {
#pragma unroll
      for (int k = 0; k < 6; ++k) {
        int c = p[(size_t)i * NN + (k << 6)];
        if (c < vmin[k]) { vmin[k] = c; imin[k] = i; }
      }
    }
  }
#pragma unroll
  for (int k = 0; k < 6; ++k) vv[k] = vmin[k];
#pragma unroll
  for (int k = 0; k < 6; ++k) {
    int r = lane + (k << 6);
    rowpick_s[r] = 0x7fffffff;
    rowfree_s[r] = 1;
    u_si[r] = 0;
  }
  lds_fence();
#pragma unroll
  for (int k = 0; k < 6; ++k) atomicMin(&rowpick_s[imin[k]], lane + (k << 6));
  lds_fence();
#pragma unroll
  for (int k = 0; k < 6; ++k) {
    int j = lane + (k << 6);
    int i1 = imin[k];
    int won = (rowpick_s[i1] == j);
    mrow_s[j] = won ? i1 : -1;
    if (won) rowfree_s[i1] = 0;
  }
  lds_fence();

  // ---- matched-row list for RT -------------------------------------------------
  int mcount = 0;
#pragma unroll
  for (int k = 0; k < 6; ++k) {
    int r = lane + (k << 6);
    int mtc = (rowfree_s[r] == 0);
    unsigned long long msk = __ballot(mtc);
    if (mtc) list_s[mcount + (int)__popcll(msk & ((1ull << lane) - 1ull))] = r;
    mcount += (int)__popcll(msk);
  }
  lds_fence();

  // ---- Phase 2: reduction transfer (prefetched rows, i32 min) ------------------
  {
    int i_cur = 0;
    if (mcount > 0) i_cur = list_s[0];
    int cf[6];
#pragma unroll
    for (int k = 0; k < 6; ++k) cf[k] = Ci[(size_t)i_cur * NN + lane + (k << 6)];
    for (int idx = 0; idx < mcount; ++idx) {
      int i = i_cur;
      int cfc[6];
#pragma unroll
      for (int k = 0; k < 6; ++k) cfc[k] = cf[k];
      int inext = (idx + 1 < mcount) ? list_s[idx + 1] : i_cur;
      i_cur = inext;
#pragma unroll
      for (int k = 0; k < 6; ++k) cf[k] = Ci[(size_t)inext * NN + lane + (k << 6)];
      int j1 = rowpick_s[i];  // uniform
      int kj = j1 >> 6, oj = j1 & 63;
      int m = 0x7FFFFFFF;
#pragma unroll
      for (int k = 0; k < 6; ++k) {
        int cur = cfc[k] - vv[k];
        bool excl = (k == kj) && (lane == oj);
        m = min(m, excl ? 0x7FFFFFFF : cur);
      }
      m = wave_min_i32(m);
      int cj1 = __builtin_amdgcn_readlane(sel6b(cfc, kj), oj);
      if (lane == oj) { SETV6(vv, kj, cj1 - m); }
      if (lane == 0) u_si[i] = m;
    }
  }
  lds_fence();

  // ---- persist state -----------------------------------------------------------
#pragma unroll
  for (int k = 0; k < 6; ++k) {
    int j = lane + (k << 6);
    stp[j] = vv[k];
    stp[NN + j] = u_si[j];
    stp[2 * NN + j] = mrow_s[j];
    stp[3 * NN + j] = rowfree_s[j];
  }
}

// ---------------- LAP kernel 2: augmenting row reduction (capped) ---------------
__global__ __launch_bounds__(64) void lap_init2_k(const int* __restrict__ costs,
                                                  int* __restrict__ st) {
  const int prob = blockIdx.x;
  const int* __restrict__ Ci = costs + (size_t)prob * NN * NN;
  int* __restrict__ stp = st + (size_t)prob * 4 * NN;
  const int lane = threadIdx.x;

  __shared__ int u_si[NN];
  __shared__ int mrow_s[NN];
  __shared__ int rowfree_s[NN];
  __shared__ int q_s[512];

  int vv[6], mr[6];

  // ---- load state ---------------------------------------------------------------
  int frl[6];
#pragma unroll
  for (int k = 0; k < 6; ++k) {
    int j = lane + (k << 6);
    vv[k] = stp[j];
    u_si[j] = stp[NN + j];
    int mrv = stp[2 * NN + j];
    mrow_s[j] = mrv;
    mr[k] = mrv;
    frl[k] = stp[3 * NN + j];
    rowfree_s[j] = frl[k];
  }
  for (int t = lane; t < 512; t += 64) q_s[t] = 0;
  int head = 0, tail = 0;
#pragma unroll
  for (int k = 0; k < 6; ++k) {
    int r = lane + (k << 6);
    int fr = frl[k];
    unsigned long long msk = __ballot(fr);
    if (fr) q_s[tail + (int)__popcll(msk & ((1ull << lane) - 1ull))] = r;
    tail += (int)__popcll(msk);
  }
  lds_fence();

  // ---- Phase 3: ARR (capped, prefetched) -----------------------------------------
  {
    int pre_for = -1, i_pre = 0;
    int cf[6];
#pragma unroll
    for (int k = 0; k < 6; ++k) cf[k] = 0;
    if (head < tail) {
      i_pre = q_s[head & 511];
      pre_for = head;
#pragma unroll
      for (int k = 0; k < 6; ++k) cf[k] = Ci[(size_t)i_pre * NN + lane + (k << 6)];
    }
    for (int it = 0; it < ARR_CAP && head < tail; ++it) {
      int i;
      int cfc[6];
      if (pre_for == head) {  // uniform
        i = i_pre;
#pragma unroll
        for (int k = 0; k < 6; ++k) cfc[k] = cf[k];
      } else {
        i = q_s[head & 511];
#pragma unroll
        for (int k = 0; k < 6; ++k) cfc[k] = Ci[(size_t)i * NN + lane + (k << 6)];
      }
      head++;
      int nxt = q_s[head & 511];
      bool pvalid = (head < tail);
      i_pre = nxt;
      pre_for = pvalid ? head : -1;
#pragma unroll
      for (int k = 0; k < 6; ++k) cf[k] = Ci[(size_t)i_pre * NN + lane + (k << 6)];

      int pk[6];
#pragma unroll
      for (int k = 0; k < 6; ++k) {
        int cur = cfc[k] - vv[k];              // >= 0 by dual feasibility
        int key = min(cur, SATK);              // real values never saturate (28-bit)
        pk[k] = (key << 3) | k;
      }
      int l1 = min(pk[0], pk[1]), h1 = max(pk[0], pk[1]);
      int l2 = min(pk[2], pk[3]), h2 = max(pk[2], pk[3]);
      int l3 = min(pk[4], pk[5]), h3 = max(pk[4], pk[5]);
      int lm1 = min(min(l1, l2), l3);
      int med = max(min(l1, l2), min(max(l1, l2), l3));
      int lm2 = min(med, min(min(h1, h2), h3));
      int m1 = lm1, m2 = lm2;
      wave_min2_i32(m1, m2);
      unsigned long long bm = __ballot(lm1 == m1);
      int src = (int)__builtin_ctzll(bm);
      int kj = m1 & 7;
      int j1 = src + (kj << 6);
      int u1 = m1 >> 3, u2 = m2 >> 3;
      int i0 = __builtin_amdgcn_readlane(sel6b(mr, kj), src);
      bool tiebad = (u1 == u2) && (i0 >= 0);
      if (!tiebad) {
        if (u1 < u2) {
          if (lane == src) { SETV6(vv, kj, vv[kj] - (u2 - u1)); }
        }
        if (lane == src) { SETV6(mr, kj, i); }
        if (lane == 0) {
          mrow_s[j1] = i;
          rowfree_s[i] = 0;
          u_si[i] = u2;
          if (i0 >= 0) { rowfree_s[i0] = 1; q_s[tail & 511] = i0; }
        }
        if (i0 >= 0) tail++;
      }
      lds_fence();
    }
  }
  lds_fence();

  // ---- persist state --------------------------------------------------------------
#pragma unroll
  for (int k = 0; k < 6; ++k) {
    int j = lane + (k << 6);
    stp[j] = vv[k];
    stp[NN + j] = u_si[j];
    stp[2 * NN + j] = mrow_s[j];
    stp[3 * NN + j] = rowfree_s[j];
  }
}

// ---------------- LAP kernel 3: shortest augmenting path + epilogue -------------
// No speculation: demand load issued immediately after winner lookup; m1-only
// min tree in the scan.
__global__ __launch_bounds__(64) void lap_sap_k(const int* __restrict__ costs,
                                                const long long* __restrict__ invA,
                                                const long long* __restrict__ invB,
                                                int* __restrict__ colofrow,  // [5][NN]
                                                int* __restrict__ mism,      // [4]
                                                const int* __restrict__ st) {
  const int prob = blockIdx.x;
  const int* __restrict__ Ci = costs + (size_t)prob * NN * NN;
  const int* __restrict__ stp = st + (size_t)prob * 4 * NN;
  const int lane = threadIdx.x;

  __shared__ int u_si[NN];
  __shared__ int mrow_s[NN];
  __shared__ int q_s[512];
  __shared__ int cofr_s[NN];
  __shared__ int ideal_s[NN];

  int vv[6], mr[6], umr[6];

  // ---- load state -----------------------------------------------------------------
  int frl[6];
#pragma unroll
  for (int k = 0; k < 6; ++k) {
    int j = lane + (k << 6);
    vv[k] = stp[j];
    u_si[j] = stp[NN + j];
    int mrv = stp[2 * NN + j];
    mrow_s[j] = mrv;
    mr[k] = mrv;
    frl[k] = stp[3 * NN + j];
  }
  lds_fence();
#pragma unroll
  for (int k = 0; k < 6; ++k) {
    int r = mr[k];
    umr[k] = (r < 0) ? 0 : u_si[max(r, 0)];
  }
  int ntodo = 0;
#pragma unroll
  for (int k = 0; k < 6; ++k) {
    int r = lane + (k << 6);
    int fr = frl[k];
    unsigned long long msk = __ballot(fr);
    if (fr) q_s[ntodo + (int)__popcll(msk & ((1ull << lane) - 1ull))] = r;
    ntodo += (int)__popcll(msk);
  }
  lds_fence();

  int csp[6];  // prefetched root row of the next tree
  if (ntodo > 0) {
    int f0 = q_s[0];
    const int* crow0 = Ci + (size_t)f0 * NN;
#pragma unroll
    for (int k = 0; k < 6; ++k) csp[k] = crow0[lane + (k << 6)];
  }

  // ---- Phase 4: Dijkstra trees (demand loads only) ----------------------------------
  for (int fi = 0; fi < ntodo; ++fi) {
    int f = q_s[fi];  // uniform
    int minv[6], dj[6], wy[6];
#pragma unroll
    for (int k = 0; k < 6; ++k) { minv[k] = BIG0; dj[k] = 0; wy[k] = -1; }
    int D = 0, markj = -1, j1 = -1;
    int ui0 = u_si[f];
    const int uif = ui0;
    int cs[6];
#pragma unroll
    for (int k = 0; k < 6; ++k) cs[k] = csp[k];
    for (;;) {
      int s = ui0 - D;
      int pk[6];
#pragma unroll
      for (int k = 0; k < 6; ++k) {
        int cur = (cs[k] - s) - vv[k];
        bool domark = ((lane + (k << 6)) == markj);
        bool used = (minv[k] == MARKV);
        bool upd = (cur < minv[k]) && !used && !domark;
        minv[k] = domark ? MARKV : (upd ? cur : minv[k]);
        dj[k] = domark ? D : dj[k];
        wy[k] = upd ? markj : wy[k];
        int diff = minv[k] - D;                // >= 0 (Dijkstra invariant)
        int key = min(diff, SATK);             // only MARK/BIG saturate
        pk[k] = (key << 3) | k;
      }
      int lm1 = min(min(min(pk[0], pk[1]), min(pk[2], pk[3])), min(pk[4], pk[5]));
      int m1 = wave_min_i32(lm1);
      unsigned long long bm = __ballot(lm1 == m1);
      int src = (int)__builtin_ctzll(bm);
      int kj = m1 & 7;
      j1 = src + (kj << 6);
      D += (m1 >> 3);
      int r = __builtin_amdgcn_readlane(sel6b(mr, kj), src);
      int ur = __builtin_amdgcn_readlane(sel6b(umr, kj), src);
      if (r < 0) break;  // free column reached
      // demand load, issued immediately (earliest possible point)
      const int* crow = Ci + (size_t)r * NN;
#pragma unroll
      for (int k = 0; k < 6; ++k) cs[k] = crow[lane + (k << 6)];
      markj = j1; ui0 = ur;
    }
    // prefetch next tree's root row (in shadow of dual update + augment walk)
    if (fi + 1 < ntodo) {
      int fn = q_s[fi + 1];
      const int* crown = Ci + (size_t)fn * NN;
#pragma unroll
      for (int k = 0; k < 6; ++k) csp[k] = crown[lane + (k << 6)];
    }
    // dual updates (pre-augmentation matching in mr[])
#pragma unroll
    for (int k = 0; k < 6; ++k) {
      if (minv[k] == MARKV) {
        int upd = D - dj[k];
        vv[k] -= upd;
        u_si[mr[k]] += upd;   // distinct rows per used col
      }
    }
    if (lane == 0) u_si[f] = uif + D;
    // augment walk: register readlane chase, fire-and-forget LDS writes
    {
      int j = j1, jprev = -1;
      for (;;) {
        int kjw = j >> 6, ojw = j & 63;
        int jp = __builtin_amdgcn_readlane(sel6b(wy, kjw), ojw);
        int rc = __builtin_amdgcn_readlane(sel6b(mr, kjw), ojw);
        if (jprev >= 0 && lane == 0) mrow_s[jprev] = rc;
        if (jp < 0) { if (lane == 0) mrow_s[j] = f; break; }
        jprev = j; j = jp;
      }
    }
    lds_fence();
#pragma unroll
    for (int k = 0; k < 6; ++k) mr[k] = mrow_s[lane + (k << 6)];
#pragma unroll
    for (int k = 0; k < 6; ++k) {
      int rr = mr[k];
      umr[k] = (rr < 0) ? 0 : u_si[max(rr, 0)];
    }
  }

  // ---- epilogue: col_of_row, ideal matching, mismatch count -------------------------
  lds_fence();
#pragma unroll
  for (int k = 0; k < 6; ++k) {
    int j = lane + (k << 6);
    cofr_s[mrow_s[j]] = j;
    ideal_s[(int)invA[j]] = (int)invB[j];
  }
  lds_fence();
  int cnt = 0;
#pragma unroll
  for (int k = 0; k < 6; ++k) {
    int r = lane + (k << 6);
    colofrow[prob * NN + r] = cofr_s[r];
    cnt += (cofr_s[r] != ideal_s[r]) ? 1 : 0;
  }
#pragma unroll
  for (int off = 1; off < 64; off <<= 1) cnt += __shfl_xor(cnt, off, 64);
  if (lane == 0 && prob < 4) mism[prob] = cnt;
}

// ---------------- finalize: total, row_ind, col_ind ----------------------------
__global__ __launch_bounds__(384) void finalize_k(const int* __restrict__ colofrow,
                                                  const int* __restrict__ mism,
                                                  float* __restrict__ out) {
  int t = threadIdx.x;
  if (t == 0) {
    const double w[4] = {1.0, 0.5, 0.25, 0.125};
    double tot = 0.0;
    for (int l = 0; l < 4; ++l) tot += w[l] * (2.0 * (double)mism[l] / (double)NN);
    out[0] = (float)tot;
  }
  out[1 + t] = (float)t;
  out[1 + NN + t] = (float)colofrow[4 * NN + t];
}

extern "C" void kernel_launch(void* const* d_in, const int* in_sizes, int n_in,
                              void* d_out, int out_size, void* d_ws, size_t ws_size,
                              hipStream_t stream) {
  const float* lat[4] = {(const float*)d_in[0], (const float*)d_in[1],
                         (const float*)d_in[2], (const float*)d_in[3]};
  const long long* invA = (const long long*)d_in[4];
  const long long* invB = (const long long*)d_in[5];

  float* ws = (float*)d_ws;
  float* cost = ws;                          // 5 * 147456 (f32 scaled -> i32 in place)
  float* norms = ws + 5 * NN * NN;           // 4 * 768
  int* colofrow = (int*)(norms + 4 * 768);   // 5 * 384
  int* mism = colofrow + 5 * NN;             // 4 (pad 8)
  int* st = mism + 8;                        // 5 * 4 * 384 solver state
  float* pbuf = (float*)(st + 5 * 4 * NN);   // 36*S*4096 floats (split-K partials)

  int K[4];
  for (int l = 0; l < 4; ++l) K[l] = in_sizes[l] / (2 * NN);

  // pick largest split factor that fits the workspace
  size_t base = (size_t)(5 * NN * NN + 4 * 768 + 5 * NN + 8 + 5 * 4 * NN);
  int S = 0;
  for (int cand = 32; cand >= 8; cand >>= 1) {
    if (ws_size >= (base + (size_t)36 * cand * 4096) * 4) { S = cand; break; }
  }

  row_norms_k<<<dim3(768, 4), 256, 0, stream>>>(
      lat[0], lat[1], lat[2], lat[3], norms, K[0], K[1], K[2], K[3]);

  if (S > 0) {
    for (int l = 0; l < 4; ++l) {
      float inv_ds = 16777216.0f / (float)K[l];  // 2^24/K, exact power of 2
      gemm_partial_k<<<dim3(6, 6, S), 256, 0, stream>>>(
          lat[l], lat[l] + (size_t)NN * K[l], pbuf, K[l], K[l] / S, S);
      cost_finalize_k<<<(NN * NN + 255) / 256, 256, 0, stream>>>(
          pbuf, norms + l * 768, norms + l * 768 + NN,
          cost + (size_t)l * NN * NN, S, inv_ds);
    }
  } else {
    for (int l = 0; l < 4; ++l) {
      float inv_ds = 16777216.0f / (float)K[l];
      gemm_cost_k<<<dim3(6, 6), 256, 0, stream>>>(
          lat[l], lat[l] + (size_t)NN * K[l], norms + l * 768, norms + l * 768 + NN,
          cost + (size_t)l * NN * NN, K[l], inv_ds);
    }
  }
  combine_k<<<(NN * NN + 255) / 256, 256, 0, stream>>>(cost);
  lap_init1_k<<<5, 64, 0, stream>>>((const int*)cost, st);
  lap_init2_k<<<5, 64, 0, stream>>>((const int*)cost, st);
  lap_sap_k<<<5, 64, 0, stream>>>((const int*)cost, invA, invB, colofrow, mism, st);
  finalize_k<<<1, NN, 0, stream>>>(colofrow, mism, (float*)d_out);
}

// Round 13
// 2760.346 us; speedup vs baseline: 1.5843x; 1.5843x over previous
//
#include <hip/hip_runtime.h>

#define NN 384
#define ARR_CAP 6000
#define CHURN_WIN 96              // ARR early-exit: no queue shrink in this many iters
#define MARKV 0x7FFFFFFF          // minv sentinel: column used in current tree
#define BIG0  0x7FFFFFF0          // minv init (must differ from MARKV)
#define SATK  ((1 << 28) - 1)     // 28-bit key: covers full cost range (<2^27.5) -> real
                                  // values NEVER saturate; only MARKV/BIG0 map to SATK.
// Costs are stored pre-scaled by 2^24 and converted to i32 in place: f32 value
// c*2^24 is an EXACT integer < 2^28. All solver arithmetic is exact i32 math ->
// identical optimum to f64-on-f32 (reference) solve (unique optimum w.p. 1).
//
// LAP split into 3 kernels (init1 = CR+RT, init2 = ARR, sap = Dijkstra) for
// rocprof phase attribution. THIS ROUND: ARR churn early-exit + endgame
// prefetch (r9 fix, lost in the r10 split) + SAP pre-reduce candidate fetch.

// uniform-index register-array write helpers
#define SETV6(a, k, val) do{ switch(k){ \
  case 0: a[0]=(val); break; case 1: a[1]=(val); break; case 2: a[2]=(val); break; \
  case 3: a[3]=(val); break; case 4: a[4]=(val); break; default: a[5]=(val); } }while(0)

__device__ __forceinline__ void lds_fence() {
  // single-wave block: lgkmcnt(0) orders LDS cross-lane; no barrier, no vmcnt drain
  asm volatile("s_waitcnt lgkmcnt(0)" ::: "memory");
}

// branchless 6-way select of a[k] (works for per-lane k too: pure cndmask)
__device__ __forceinline__ int sel6b(const int (&a)[6], int k) {
  int x01 = (k & 1) ? a[1] : a[0];
  int x23 = (k & 1) ? a[3] : a[2];
  int x45 = (k & 1) ? a[5] : a[4];
  int xlo = (k & 2) ? x23 : x01;
  return (k & 4) ? x45 : xlo;
}

template<int CTRL>
__device__ __forceinline__ int dpp_i32(int x) {
  // lanes without a valid DPP source keep INT_MAX -> never win the min
  return __builtin_amdgcn_update_dpp(0x7FFFFFFF, x, CTRL, 0xF, 0xF, false);
}

// stages: xor1, xor2 (quads), ror4, ror8 (row of 16), bcast15, bcast31 (merge rows)
__device__ __forceinline__ int wave_min_i32(int m) {
#define ST(C) { int o = dpp_i32<C>(m); m = min(m, o); }
  ST(0xB1) ST(0x4E) ST(0x124) ST(0x128) ST(0x142) ST(0x143)
#undef ST
  return __builtin_amdgcn_readlane(m, 63);
}

// (min, second-min) over disjoint per-lane candidate sets; results broadcast
__device__ __forceinline__ void wave_min2_i32(int& m1, int& m2) {
#define ST(C) { int o1 = dpp_i32<C>(m1); int o2 = dpp_i32<C>(m2); \
                int hi = max(m1, o1); m1 = min(m1, o1); m2 = min(min(m2, o2), hi); }
  ST(0xB1) ST(0x4E) ST(0x124) ST(0x128) ST(0x142) ST(0x143)
#undef ST
  m1 = __builtin_amdgcn_readlane(m1, 63);
  m2 = __builtin_amdgcn_readlane(m2, 63);
}

// ---------------- row norms: 4 layers fused, X is [768][K] each -----------------
__global__ __launch_bounds__(256) void row_norms_k(const float* __restrict__ x0,
                                                   const float* __restrict__ x1,
                                                   const float* __restrict__ x2,
                                                   const float* __restrict__ x3,
                                                   float* __restrict__ out,
                                                   int K0, int K1, int K2, int K3) {
  int layer = blockIdx.y;
  const float* X = layer == 0 ? x0 : layer == 1 ? x1 : layer == 2 ? x2 : x3;
  int K = layer == 0 ? K0 : layer == 1 ? K1 : layer == 2 ? K2 : K3;
  int row = blockIdx.x;
  int tid = threadIdx.x;
  const float4* xp = (const float4*)(X + (size_t)row * K);
  int K4 = K >> 2;
  float s = 0.f;
  for (int k = tid; k < K4; k += 256) {
    float4 x = xp[k];
    s = fmaf(x.x, x.x, s); s = fmaf(x.y, x.y, s);
    s = fmaf(x.z, x.z, s); s = fmaf(x.w, x.w, s);
  }
  __shared__ float red[256];
  red[tid] = s;
  __syncthreads();
  for (int st = 128; st > 0; st >>= 1) {
    if (tid < st) red[tid] += red[tid + st];
    __syncthreads();
  }
  if (tid == 0) out[layer * 768 + row] = red[0];
}

// ---------------- split-K GEMM partial: 64x64 tile, K-slice ---------------------
__global__ __launch_bounds__(256) void gemm_partial_k(const float* __restrict__ A,
                                                      const float* __restrict__ B,
                                                      float* __restrict__ pbuf,
                                                      int K, int kslice, int S) {
  __shared__ float As[16][64];
  __shared__ float Bs[16][64];
  const int tid = threadIdx.x;
  const int row0 = blockIdx.y * 64;
  const int col0 = blockIdx.x * 64;
  const int sz = blockIdx.z;
  const int tm = (tid >> 4) << 2;
  const int tn = (tid & 15) << 2;
  const int lr = tid >> 2;
  const int lk = (tid & 3) << 2;
  const float* ap = A + (size_t)(row0 + lr) * K + (size_t)sz * kslice + lk;
  const float* bp = B + (size_t)(col0 + lr) * K + (size_t)sz * kslice + lk;
  float acc[4][4] = {};
  for (int k0 = 0; k0 < kslice; k0 += 16) {
    float4 av = *(const float4*)(ap + k0);
    float4 bv = *(const float4*)(bp + k0);
    __syncthreads();
    As[lk + 0][lr] = av.x; As[lk + 1][lr] = av.y; As[lk + 2][lr] = av.z; As[lk + 3][lr] = av.w;
    Bs[lk + 0][lr] = bv.x; Bs[lk + 1][lr] = bv.y; Bs[lk + 2][lr] = bv.z; Bs[lk + 3][lr] = bv.w;
    __syncthreads();
    float t[4][4] = {};
#pragma unroll
    for (int kk = 0; kk < 16; ++kk) {
      float4 a = *(const float4*)&As[kk][tm];
      float4 b = *(const float4*)&Bs[kk][tn];
      t[0][0] = fmaf(a.x, b.x, t[0][0]); t[0][1] = fmaf(a.x, b.y, t[0][1]);
      t[0][2] = fmaf(a.x, b.z, t[0][2]); t[0][3] = fmaf(a.x, b.w, t[0][3]);
      t[1][0] = fmaf(a.y, b.x, t[1][0]); t[1][1] = fmaf(a.y, b.y, t[1][1]);
      t[1][2] = fmaf(a.y, b.z, t[1][2]); t[1][3] = fmaf(a.y, b.w, t[1][3]);
      t[2][0] = fmaf(a.z, b.x, t[2][0]); t[2][1] = fmaf(a.z, b.y, t[2][1]);
      t[2][2] = fmaf(a.z, b.z, t[2][2]); t[2][3] = fmaf(a.z, b.w, t[2][3]);
      t[3][0] = fmaf(a.w, b.x, t[3][0]); t[3][1] = fmaf(a.w, b.y, t[3][1]);
      t[3][2] = fmaf(a.w, b.z, t[3][2]); t[3][3] = fmaf(a.w, b.w, t[3][3]);
    }
#pragma unroll
    for (int m = 0; m < 4; ++m)
#pragma unroll
      for (int n = 0; n < 4; ++n) acc[m][n] += t[m][n];
  }
  float* pb = pbuf + (((size_t)(blockIdx.y * 6 + blockIdx.x) * S + sz) << 12);
#pragma unroll
  for (int m = 0; m < 4; ++m)
#pragma unroll
    for (int n = 0; n < 4; ++n)
      pb[((tm + m) << 6) | (tn + n)] = acc[m][n];
}

// ---------------- finalize cost from partials; output scaled by 2^24 ------------
__global__ __launch_bounds__(256) void cost_finalize_k(const float* __restrict__ pbuf,
                                                       const float* __restrict__ sa,
                                                       const float* __restrict__ sb,
                                                       float* __restrict__ C,
                                                       int S, float inv_ds) {
  int idx = blockIdx.x * 256 + threadIdx.x;
  if (idx >= NN * NN) return;
  int i = idx / NN;
  int j = idx - i * NN;
  int t = (i >> 6) * 6 + (j >> 6);
  int w = ((i & 63) << 6) | (j & 63);
  const float* p = pbuf + ((size_t)t * S << 12) + w;
  float dot = 0.f;
  for (int s = 0; s < S; ++s) dot += p[(size_t)s << 12];
  float sq = (sa[i] - 2.0f * dot) + sb[j];
  C[idx] = fmaxf(sq, 0.0f) * inv_ds;   // inv_ds = 2^24/K (pow2) -> exact scaling
}

// ---------------- fallback single-pass cost GEMM (if ws too small) --------------
__global__ __launch_bounds__(256) void gemm_cost_k(const float* __restrict__ A,
                                                   const float* __restrict__ B,
                                                   const float* __restrict__ sa,
                                                   const float* __restrict__ sb,
                                                   float* __restrict__ C,
                                                   int K, float inv_ds) {
  __shared__ float As[16][64];
  __shared__ float Bs[16][64];
  const int tid = threadIdx.x;
  const int row0 = blockIdx.y * 64;
  const int col0 = blockIdx.x * 64;
  const int tm = (tid >> 4) << 2;
  const int tn = (tid & 15) << 2;
  const int lr = tid >> 2;
  const int lk = (tid & 3) << 2;
  const float* ap = A + (size_t)(row0 + lr) * K + lk;
  const float* bp = B + (size_t)(col0 + lr) * K + lk;
  float acc[4][4] = {};
  for (int k0 = 0; k0 < K; k0 += 16) {
    float4 av = *(const float4*)(ap + k0);
    float4 bv = *(const float4*)(bp + k0);
    __syncthreads();
    As[lk + 0][lr] = av.x; As[lk + 1][lr] = av.y; As[lk + 2][lr] = av.z; As[lk + 3][lr] = av.w;
    Bs[lk + 0][lr] = bv.x; Bs[lk + 1][lr] = bv.y; Bs[lk + 2][lr] = bv.z; Bs[lk + 3][lr] = bv.w;
    __syncthreads();
#pragma unroll
    for (int kk = 0; kk < 16; ++kk) {
      float4 a = *(const float4*)&As[kk][tm];
      float4 b = *(const float4*)&Bs[kk][tn];
      acc[0][0] = fmaf(a.x, b.x, acc[0][0]); acc[0][1] = fmaf(a.x, b.y, acc[0][1]);
      acc[0][2] = fmaf(a.x, b.z, acc[0][2]); acc[0][3] = fmaf(a.x, b.w, acc[0][3]);
      acc[1][0] = fmaf(a.y, b.x, acc[1][0]); acc[1][1] = fmaf(a.y, b.y, acc[1][1]);
      acc[1][2] = fmaf(a.y, b.z, acc[1][2]); acc[1][3] = fmaf(a.y, b.w, acc[1][3]);
      acc[2][0] = fmaf(a.z, b.x, acc[2][0]); acc[2][1] = fmaf(a.z, b.y, acc[2][1]);
      acc[2][2] = fmaf(a.z, b.z, acc[2][2]); acc[2][3] = fmaf(a.z, b.w, acc[2][3]);
      acc[3][0] = fmaf(a.w, b.x, acc[3][0]); acc[3][1] = fmaf(a.w, b.y, acc[3][1]);
      acc[3][2] = fmaf(a.w, b.z, acc[3][2]); acc[3][3] = fmaf(a.w, b.w, acc[3][3]);
    }
  }
#pragma unroll
  for (int m = 0; m < 4; ++m) {
    int i = row0 + tm + m;
    float sai = sa[i];
#pragma unroll
    for (int n = 0; n < 4; ++n) {
      int j = col0 + tn + n;
      float sq = (sai - 2.0f * acc[m][n]) + sb[j];
      C[i * NN + j] = fmaxf(sq, 0.0f) * inv_ds;
    }
  }
}

// ---- combine (f32, rounding identical to reference since scale is pow2) then
//      convert ALL 5 matrices to i32 IN PLACE (exact: values are integral f32) --
__global__ __launch_bounds__(256) void combine_k(float* __restrict__ cost) {
  int idx = blockIdx.x * 256 + threadIdx.x;
  if (idx < NN * NN) {
    float c0 = cost[idx];
    float c1 = cost[1 * NN * NN + idx];
    float c2 = cost[2 * NN * NN + idx];
    float c3 = cost[3 * NN * NN + idx];
    float cc = c0 + 0.5f * c1 + 0.25f * c2 + 0.125f * c3;
    int* ci = (int*)cost;
    ci[idx] = (int)c0;
    ci[1 * NN * NN + idx] = (int)c1;
    ci[2 * NN * NN + idx] = (int)c2;
    ci[3 * NN * NN + idx] = (int)c3;
    ci[4 * NN * NN + idx] = (int)cc;
  }
}

// st layout per problem (stride 4*NN ints): [0,NN)=v  [NN,2NN)=u  [2NN,3NN)=mrow
// [3NN,4NN)=rowfree
// ---------------- LAP kernel 1: column reduction + reduction transfer -----------
__global__ __launch_bounds__(64) void lap_init1_k(const int* __restrict__ costs,
                                                  int* __restrict__ st) {
  const int prob = blockIdx.x;
  const int* __restrict__ Ci = costs + (size_t)prob * NN * NN;
  int* __restrict__ stp = st + (size_t)prob * 4 * NN;
  const int lane = threadIdx.x;

  __shared__ int u_si[NN];
  __shared__ int mrow_s[NN];
  __shared__ int rowpick_s[NN];
  __shared__ int rowfree_s[NN];
  __shared__ int list_s[NN];

  int vv[6];

  // ---- Phase 1: column reduction ---------------------------------------------
  int vmin[6]; int imin[6];
#pragma unroll
  for (int k = 0; k < 6; ++k) { vmin[k] = 0x7FFFFFFF; imin[k] = 0; }
  {
    const int* p = Ci + lane;
#pragma unroll 8
    for (int i = 0; i < NN; ++i) {
#pragma unroll
      for (int k = 0; k < 6; ++k) {
        int c = p[(size_t)i * NN + (k << 6)];
        if (c < vmin[k]) { vmin[k] = c; imin[k] = i; }
      }
    }
  }
#pragma unroll
  for (int k = 0; k < 6; ++k) vv[k] = vmin[k];
#pragma unroll
  for (int k = 0; k < 6; ++k) {
    int r = lane + (k << 6);
    rowpick_s[r] = 0x7fffffff;
    rowfree_s[r] = 1;
    u_si[r] = 0;
  }
  lds_fence();
#pragma unroll
  for (int k = 0; k < 6; ++k) atomicMin(&rowpick_s[imin[k]], lane + (k << 6));
  lds_fence();
#pragma unroll
  for (int k = 0; k < 6; ++k) {
    int j = lane + (k << 6);
    int i1 = imin[k];
    int won = (rowpick_s[i1] == j);
    mrow_s[j] = won ? i1 : -1;
    if (won) rowfree_s[i1] = 0;
  }
  lds_fence();

  // ---- matched-row list for RT -------------------------------------------------
  int mcount = 0;
#pragma unroll
  for (int k = 0; k < 6; ++k) {
    int r = lane + (k << 6);
    int mtc = (rowfree_s[r] == 0);
    unsigned long long msk = __ballot(mtc);
    if (mtc) list_s[mcount + (int)__popcll(msk & ((1ull << lane) - 1ull))] = r;
    mcount += (int)__popcll(msk);
  }
  lds_fence();

  // ---- Phase 2: reduction transfer (prefetched rows, i32 min) ------------------
  {
    int i_cur = 0;
    if (mcount > 0) i_cur = list_s[0];
    int cf[6];
#pragma unroll
    for (int k = 0; k < 6; ++k) cf[k] = Ci[(size_t)i_cur * NN + lane + (k << 6)];
    for (int idx = 0; idx < mcount; ++idx) {
      int i = i_cur;
      int cfc[6];
#pragma unroll
      for (int k = 0; k < 6; ++k) cfc[k] = cf[k];
      int inext = (idx + 1 < mcount) ? list_s[idx + 1] : i_cur;
      i_cur = inext;
#pragma unroll
      for (int k = 0; k < 6; ++k) cf[k] = Ci[(size_t)inext * NN + lane + (k << 6)];
      int j1 = rowpick_s[i];  // uniform
      int kj = j1 >> 6, oj = j1 & 63;
      int m = 0x7FFFFFFF;
#pragma unroll
      for (int k = 0; k < 6; ++k) {
        int cur = cfc[k] - vv[k];
        bool excl = (k == kj) && (lane == oj);
        m = min(m, excl ? 0x7FFFFFFF : cur);
      }
      m = wave_min_i32(m);
      int cj1 = __builtin_amdgcn_readlane(sel6b(cfc, kj), oj);
      if (lane == oj) { SETV6(vv, kj, cj1 - m); }
      if (lane == 0) u_si[i] = m;
    }
  }
  lds_fence();

  // ---- persist state -----------------------------------------------------------
#pragma unroll
  for (int k = 0; k < 6; ++k) {
    int j = lane + (k << 6);
    stp[j] = vv[k];
    stp[NN + j] = u_si[j];
    stp[2 * NN + j] = mrow_s[j];
    stp[3 * NN + j] = rowfree_s[j];
  }
}

// ---------------- LAP kernel 2: augmenting row reduction --------------------------
// Churn early-exit + endgame prefetch + pvalid guard.
__global__ __launch_bounds__(64) void lap_init2_k(const int* __restrict__ costs,
                                                  int* __restrict__ st) {
  const int prob = blockIdx.x;
  const int* __restrict__ Ci = costs + (size_t)prob * NN * NN;
  int* __restrict__ stp = st + (size_t)prob * 4 * NN;
  const int lane = threadIdx.x;

  __shared__ int u_si[NN];
  __shared__ int mrow_s[NN];
  __shared__ int rowfree_s[NN];
  __shared__ int q_s[512];

  int vv[6], mr[6];

  // ---- load state ---------------------------------------------------------------
  int frl[6];
#pragma unroll
  for (int k = 0; k < 6; ++k) {
    int j = lane + (k << 6);
    vv[k] = stp[j];
    u_si[j] = stp[NN + j];
    int mrv = stp[2 * NN + j];
    mrow_s[j] = mrv;
    mr[k] = mrv;
    frl[k] = stp[3 * NN + j];
    rowfree_s[j] = frl[k];
  }
  for (int t = lane; t < 512; t += 64) q_s[t] = 0;
  int head = 0, tail = 0;
#pragma unroll
  for (int k = 0; k < 6; ++k) {
    int r = lane + (k << 6);
    int fr = frl[k];
    unsigned long long msk = __ballot(fr);
    if (fr) q_s[tail + (int)__popcll(msk & ((1ull << lane) - 1ull))] = r;
    tail += (int)__popcll(msk);
  }
  lds_fence();

  // ---- Phase 3: ARR (early-exit on churn, full prefetch coverage) ----------------
  {
    int pre_for = -1, i_pre = 0;
    int last_shrink = 0;
    int cf[6];
#pragma unroll
    for (int k = 0; k < 6; ++k) cf[k] = 0;
    if (head < tail) {
      i_pre = q_s[head & 511];
      pre_for = head;
#pragma unroll
      for (int k = 0; k < 6; ++k) cf[k] = Ci[(size_t)i_pre * NN + lane + (k << 6)];
    }
    for (int it = 0; it < ARR_CAP && head < tail; ++it) {
      if (it - last_shrink > CHURN_WIN) break;   // churn tail -> hand to SAP
      int i;
      int cfc[6];
      if (pre_for == head) {  // uniform
        i = i_pre;
#pragma unroll
        for (int k = 0; k < 6; ++k) cfc[k] = cf[k];
      } else {
        i = q_s[head & 511];
#pragma unroll
        for (int k = 0; k < 6; ++k) cfc[k] = Ci[(size_t)i * NN + lane + (k << 6)];
      }
      head++;
      int nxt = q_s[head & 511];
      bool pvalid = (head < tail);
      i_pre = nxt;
      pre_for = pvalid ? head : -1;
      if (pvalid) {
#pragma unroll
        for (int k = 0; k < 6; ++k) cf[k] = Ci[(size_t)i_pre * NN + lane + (k << 6)];
      }

      int pk[6];
#pragma unroll
      for (int k = 0; k < 6; ++k) {
        int cur = cfc[k] - vv[k];              // >= 0 by dual feasibility
        int key = min(cur, SATK);              // real values never saturate (28-bit)
        pk[k] = (key << 3) | k;
      }
      int l1 = min(pk[0], pk[1]), h1 = max(pk[0], pk[1]);
      int l2 = min(pk[2], pk[3]), h2 = max(pk[2], pk[3]);
      int l3 = min(pk[4], pk[5]), h3 = max(pk[4], pk[5]);
      int lm1 = min(min(l1, l2), l3);
      int med = max(min(l1, l2), min(max(l1, l2), l3));
      int lm2 = min(med, min(min(h1, h2), h3));
      int m1 = lm1, m2 = lm2;
      wave_min2_i32(m1, m2);
      unsigned long long bm = __ballot(lm1 == m1);
      int src = (int)__builtin_ctzll(bm);
      int kj = m1 & 7;
      int j1 = src + (kj << 6);
      int u1 = m1 >> 3, u2 = m2 >> 3;
      int i0 = __builtin_amdgcn_readlane(sel6b(mr, kj), src);
      bool tiebad = (u1 == u2) && (i0 >= 0);
      if (!tiebad) {
        if (u1 < u2) {
          if (lane == src) { SETV6(vv, kj, vv[kj] - (u2 - u1)); }
        }
        if (lane == src) { SETV6(mr, kj, i); }
        if (lane == 0) {
          mrow_s[j1] = i;
          rowfree_s[i] = 0;
          u_si[i] = u2;
          if (i0 >= 0) { rowfree_s[i0] = 1; q_s[tail & 511] = i0; }
        }
        if (i0 >= 0) {
          tail++;
          // endgame prefetch: queue was empty pre-push -> next pop is i0
          if (pre_for < 0) {
            i_pre = i0; pre_for = head;
#pragma unroll
            for (int k = 0; k < 6; ++k) cf[k] = Ci[(size_t)i0 * NN + lane + (k << 6)];
          }
        } else {
          last_shrink = it;   // fresh column assigned -> queue shrank
        }
      } else {
        last_shrink = it;     // tie-drop -> queue shrank (row left for SAP)
      }
      lds_fence();
    }
  }
  lds_fence();

  // ---- persist state --------------------------------------------------------------
#pragma unroll
  for (int k = 0; k < 6; ++k) {
    int j = lane + (k << 6);
    stp[j] = vv[k];
    stp[NN + j] = u_si[j];
    stp[2 * NN + j] = mrow_s[j];
    stp[3 * NN + j] = rowfree_s[j];
  }
}

// ---------------- LAP kernel 3: shortest augmenting path + epilogue -------------
// No speculation; per-lane candidate mr/umr fetched BEFORE the butterfly (each
// lane's local-min column is self-owned), shortening the post-reduce chain.
__global__ __launch_bounds__(64) void lap_sap_k(const int* __restrict__ costs,
                                                const long long* __restrict__ invA,
                                                const long long* __restrict__ invB,
                                                int* __restrict__ colofrow,  // [5][NN]
                                                int* __restrict__ mism,      // [4]
                                                const int* __restrict__ st) {
  const int prob = blockIdx.x;
  const int* __restrict__ Ci = costs + (size_t)prob * NN * NN;
  const int* __restrict__ stp = st + (size_t)prob * 4 * NN;
  const int lane = threadIdx.x;

  __shared__ int u_si[NN];
  __shared__ int mrow_s[NN];
  __shared__ int q_s[512];
  __shared__ int cofr_s[NN];
  __shared__ int ideal_s[NN];

  int vv[6], mr[6], umr[6];

  // ---- load state -----------------------------------------------------------------
  int frl[6];
#pragma unroll
  for (int k = 0; k < 6; ++k) {
    int j = lane + (k << 6);
    vv[k] = stp[j];
    u_si[j] = stp[NN + j];
    int mrv = stp[2 * NN + j];
    mrow_s[j] = mrv;
    mr[k] = mrv;
    frl[k] = stp[3 * NN + j];
  }
  lds_fence();
#pragma unroll
  for (int k = 0; k < 6; ++k) {
    int r = mr[k];
    umr[k] = (r < 0) ? 0 : u_si[max(r, 0)];
  }
  int ntodo = 0;
#pragma unroll
  for (int k = 0; k < 6; ++k) {
    int r = lane + (k << 6);
    int fr = frl[k];
    unsigned long long msk = __ballot(fr);
    if (fr) q_s[ntodo + (int)__popcll(msk & ((1ull << lane) - 1ull))] = r;
    ntodo += (int)__popcll(msk);
  }
  lds_fence();

  int csp[6];  // prefetched root row of the next tree
  if (ntodo > 0) {
    int f0 = q_s[0];
    const int* crow0 = Ci + (size_t)f0 * NN;
#pragma unroll
    for (int k = 0; k < 6; ++k) csp[k] = crow0[lane + (k << 6)];
  }

  // ---- Phase 4: Dijkstra trees (demand loads only) ----------------------------------
  for (int fi = 0; fi < ntodo; ++fi) {
    int f = q_s[fi];  // uniform
    int minv[6], dj[6], wy[6];
#pragma unroll
    for (int k = 0; k < 6; ++k) { minv[k] = BIG0; dj[k] = 0; wy[k] = -1; }
    int D = 0, markj = -1, j1 = -1;
    int ui0 = u_si[f];
    const int uif = ui0;
    int cs[6];
#pragma unroll
    for (int k = 0; k < 6; ++k) cs[k] = csp[k];
    for (;;) {
      int s = ui0 - D;
      int pk[6];
#pragma unroll
      for (int k = 0; k < 6; ++k) {
        int cur = (cs[k] - s) - vv[k];
        bool domark = ((lane + (k << 6)) == markj);
        bool used = (minv[k] == MARKV);
        bool upd = (cur < minv[k]) && !used && !domark;
        minv[k] = domark ? MARKV : (upd ? cur : minv[k]);
        dj[k] = domark ? D : dj[k];
        wy[k] = upd ? markj : wy[k];
        int diff = minv[k] - D;                // >= 0 (Dijkstra invariant)
        int key = min(diff, SATK);             // only MARK/BIG saturate
        pk[k] = (key << 3) | k;
      }
      int lm1 = min(min(min(pk[0], pk[1]), min(pk[2], pk[3])), min(pk[4], pk[5]));
      // per-lane candidate lookups (self-owned col) -- off the critical path,
      // overlap with the butterfly below
      int kb = lm1 & 7;
      int rc_ = sel6b(mr, kb);
      int uc_ = sel6b(umr, kb);
      int m1 = wave_min_i32(lm1);
      unsigned long long bm = __ballot(lm1 == m1);
      int src = (int)__builtin_ctzll(bm);
      int kj = m1 & 7;
      j1 = src + (kj << 6);
      D += (m1 >> 3);
      int r = __builtin_amdgcn_readlane(rc_, src);
      int ur = __builtin_amdgcn_readlane(uc_, src);
      if (r < 0) break;  // free column reached
      // demand load, issued immediately (earliest possible point)
      const int* crow = Ci + (size_t)r * NN;
#pragma unroll
      for (int k = 0; k < 6; ++k) cs[k] = crow[lane + (k << 6)];
      markj = j1; ui0 = ur;
    }
    // prefetch next tree's root row (in shadow of dual update + augment walk)
    if (fi + 1 < ntodo) {
      int fn = q_s[fi + 1];
      const int* crown = Ci + (size_t)fn * NN;
#pragma unroll
      for (int k = 0; k < 6; ++k) csp[k] = crown[lane + (k << 6)];
    }
    // dual updates (pre-augmentation matching in mr[])
#pragma unroll
    for (int k = 0; k < 6; ++k) {
      if (minv[k] == MARKV) {
        int upd = D - dj[k];
        vv[k] -= upd;
        u_si[mr[k]] += upd;   // distinct rows per used col
      }
    }
    if (lane == 0) u_si[f] = uif + D;
    // augment walk: register readlane chase, fire-and-forget LDS writes
    {
      int j = j1, jprev = -1;
      for (;;) {
        int kjw = j >> 6, ojw = j & 63;
        int jp = __builtin_amdgcn_readlane(sel6b(wy, kjw), ojw);
        int rc = __builtin_amdgcn_readlane(sel6b(mr, kjw), ojw);
        if (jprev >= 0 && lane == 0) mrow_s[jprev] = rc;
        if (jp < 0) { if (lane == 0) mrow_s[j] = f; break; }
        jprev = j; j = jp;
      }
    }
    lds_fence();
#pragma unroll
    for (int k = 0; k < 6; ++k) mr[k] = mrow_s[lane + (k << 6)];
#pragma unroll
    for (int k = 0; k < 6; ++k) {
      int rr = mr[k];
      umr[k] = (rr < 0) ? 0 : u_si[max(rr, 0)];
    }
  }

  // ---- epilogue: col_of_row, ideal matching, mismatch count -------------------------
  lds_fence();
#pragma unroll
  for (int k = 0; k < 6; ++k) {
    int j = lane + (k << 6);
    cofr_s[mrow_s[j]] = j;
    ideal_s[(int)invA[j]] = (int)invB[j];
  }
  lds_fence();
  int cnt = 0;
#pragma unroll
  for (int k = 0; k < 6; ++k) {
    int r = lane + (k << 6);
    colofrow[prob * NN + r] = cofr_s[r];
    cnt += (cofr_s[r] != ideal_s[r]) ? 1 : 0;
  }
#pragma unroll
  for (int off = 1; off < 64; off <<= 1) cnt += __shfl_xor(cnt, off, 64);
  if (lane == 0 && prob < 4) mism[prob] = cnt;
}

// ---------------- finalize: total, row_ind, col_ind ----------------------------
__global__ __launch_bounds__(384) void finalize_k(const int* __restrict__ colofrow,
                                                  const int* __restrict__ mism,
                                                  float* __restrict__ out) {
  int t = threadIdx.x;
  if (t == 0) {
    const double w[4] = {1.0, 0.5, 0.25, 0.125};
    double tot = 0.0;
    for (int l = 0; l < 4; ++l) tot += w[l] * (2.0 * (double)mism[l] / (double)NN);
    out[0] = (float)tot;
  }
  out[1 + t] = (float)t;
  out[1 + NN + t] = (float)colofrow[4 * NN + t];
}

extern "C" void kernel_launch(void* const* d_in, const int* in_sizes, int n_in,
                              void* d_out, int out_size, void* d_ws, size_t ws_size,
                              hipStream_t stream) {
  const float* lat[4] = {(const float*)d_in[0], (const float*)d_in[1],
                         (const float*)d_in[2], (const float*)d_in[3]};
  const long long* invA = (const long long*)d_in[4];
  const long long* invB = (const long long*)d_in[5];

  float* ws = (float*)d_ws;
  float* cost = ws;                          // 5 * 147456 (f32 scaled -> i32 in place)
  float* norms = ws + 5 * NN * NN;           // 4 * 768
  int* colofrow = (int*)(norms + 4 * 768);   // 5 * 384
  int* mism = colofrow + 5 * NN;             // 4 (pad 8)
  int* st = mism + 8;                        // 5 * 4 * 384 solver state
  float* pbuf = (float*)(st + 5 * 4 * NN);   // 36*S*4096 floats (split-K partials)

  int K[4];
  for (int l = 0; l < 4; ++l) K[l] = in_sizes[l] / (2 * NN);

  // pick largest split factor that fits the workspace
  size_t base = (size_t)(5 * NN * NN + 4 * 768 + 5 * NN + 8 + 5 * 4 * NN);
  int S = 0;
  for (int cand = 32; cand >= 8; cand >>= 1) {
    if (ws_size >= (base + (size_t)36 * cand * 4096) * 4) { S = cand; break; }
  }

  row_norms_k<<<dim3(768, 4), 256, 0, stream>>>(
      lat[0], lat[1], lat[2], lat[3], norms, K[0], K[1], K[2], K[3]);

  if (S > 0) {
    for (int l = 0; l < 4; ++l) {
      float inv_ds = 16777216.0f / (float)K[l];  // 2^24/K, exact power of 2
      gemm_partial_k<<<dim3(6, 6, S), 256, 0, stream>>>(
          lat[l], lat[l] + (size_t)NN * K[l], pbuf, K[l], K[l] / S, S);
      cost_finalize_k<<<(NN * NN + 255) / 256, 256, 0, stream>>>(
          pbuf, norms + l * 768, norms + l * 768 + NN,
          cost + (size_t)l * NN * NN, S, inv_ds);
    }
  } else {
    for (int l = 0; l < 4; ++l) {
      float inv_ds = 16777216.0f / (float)K[l];
      gemm_cost_k<<<dim3(6, 6), 256, 0, stream>>>(
          lat[l], lat[l] + (size_t)NN * K[l], norms + l * 768, norms + l * 768 + NN,
          cost + (size_t)l * NN * NN, K[l], inv_ds);
    }
  }
  combine_k<<<(NN * NN + 255) / 256, 256, 0, stream>>>(cost);
  lap_init1_k<<<5, 64, 0, stream>>>((const int*)cost, st);
  lap_init2_k<<<5, 64, 0, stream>>>((const int*)cost, st);
  lap_sap_k<<<5, 64, 0, stream>>>((const int*)cost, invA, invB, colofrow, mism, st);
  finalize_k<<<1, NN, 0, stream>>>(colofrow, mism, (float*)d_out);
}